// Round 13
// baseline (682.866 us; speedup 1.0000x reference)
//
#include <hip/hip_runtime.h>
#include <hip/hip_bf16.h>
#include <math.h>

#define CIN 128
#define COUT 64
#define BM 128
#define KC 64
#define BSAMP 64      // samples in batch (fixed by problem)
#define NFINE 10242   // fine nodes per sample (fixed by problem)
#define NCOARSE 2562  // coarse nodes per sample (fixed by problem)
#define NRNG 4        // node-ranges per sample
#define RS 2561       // ceil(NFINE / NRNG)
#define HT 1024       // threads for build kernel
#define NCLS 17       // degree classes 0..15 and >=16
#define SEGCAP 20480  // slots per (sample,range) segment; mean 15360, sigma ~107

typedef float f32x4 __attribute__((ext_vector_type(4)));

// cur[0..255] = segment cursors, cur[256] = gctr
__global__ void k_zero(int* __restrict__ cur) {
    if (threadIdx.x < 257) cur[threadIdx.x] = 0;
}

// Bucket-scatter prep: pack each edge as (dst_range_local << 18) | (coarse_row+1),
// and append it to its (sample, dst-range) segment. Cursor atomics are
// wave-aggregated via ballot (4 atomics per wave per component group).
// inv is analytic: src local < NCOARSE  <=>  coarse row b*NCOARSE + local.
__global__ __launch_bounds__(256) void k_prep(const int4* __restrict__ src4, const int4* __restrict__ dst4,
                                              unsigned* __restrict__ pk, int* __restrict__ cur,
                                              int EPS, int bps) {
    int b  = blockIdx.x / bps;
    int il = (blockIdx.x % bps) * 256 + threadIdx.x;
    int n4 = EPS / 4;
    bool valid = il < n4;
    int lane = threadIdx.x & 63;
    unsigned long long lmask = (1ull << lane) - 1ull;
    size_t i = (size_t)b * n4 + (valid ? il : 0);
    int4 s = src4[i], d = dst4[i];
    int base = b * NFINE;
#define COMP(c) { \
    int ls = d.c - base; \
    bool ve = valid && ((unsigned)ls < (unsigned)NFINE); \
    int rri = ve ? (ls / RS) : -1; \
    int sl = s.c - base; \
    unsigned rc = ((unsigned)sl < (unsigned)NCOARSE) ? (unsigned)(b * NCOARSE + sl + 1) : 0u; \
    unsigned pv = ((unsigned)(ls - rri * RS) << 18) | rc; \
    for (int rr = 0; rr < NRNG; ++rr) { \
        unsigned long long m = __ballot(ve && (rri == rr)); \
        if (m) { \
            int leader = __ffsll((unsigned long long)m) - 1; \
            int cnt = __popcll(m); \
            int old = 0; \
            if (lane == leader) old = atomicAdd(&cur[b * NRNG + rr], cnt); \
            old = __shfl(old, leader); \
            if (ve && rri == rr) { \
                int pos = old + (int)__popcll(m & lmask); \
                if (pos < SEGCAP) pk[(size_t)(b * NRNG + rr) * SEGCAP + pos] = pv; \
            } \
        } \
    } }
    COMP(x) COMP(y) COMP(z) COMP(w)
#undef COMP
}

// One block per (sample, node-range), reading ONLY its own segment.
// Pass 1: LDS histogram (deg low16 | coarse-src count high16).
// Then block scan + one global atomic alloc, meta/normc/self-entry writes,
// degree-class bucketing into ord[] (uniform-m gather waves).
// Pass 2: re-read segment (L2-hot, ~80 KB) and assign vals2 slots.
// Entries written as (r, rsqrt(deg_dst)); k_coef folds in normc[r] afterwards.
__global__ __launch_bounds__(HT) void k_build(const unsigned* __restrict__ pk, const int* __restrict__ cur,
                                              int2* __restrict__ meta, float* __restrict__ normc,
                                              int2* __restrict__ vals2, int* __restrict__ ord,
                                              int* __restrict__ gctr) {
    __shared__ int   lh[RS];      // counts, later cursors
    __shared__ float rsd[RS];     // rsqrt(deg) per local node
    __shared__ int   sm[HT];
    __shared__ int   ccnt[NCLS];
    __shared__ int   gbase;
    int t = threadIdx.x;
    int b = blockIdx.x / NRNG, r = blockIdx.x % NRNG;
    int lo = r * RS;
    int nlocal = min(RS, NFINE - lo);
    int rebase = b * NFINE + lo;
    for (int j = t; j < nlocal; j += HT) lh[j] = 0;
    if (t < NCLS) ccnt[t] = 0;
    __syncthreads();

    const unsigned* seg = pk + (size_t)(b * NRNG + r) * SEGCAP;
    int ne = min(cur[b * NRNG + r], SEGCAP);
    for (int i = t; i < ne; i += HT) {
        unsigned u = seg[i];
        int l = (int)(u >> 18);
        int rc = (int)(u & 0x3FFFFu);
        if (l < nlocal) atomicAdd(&lh[l], 1 + (rc ? 65536 : 0));
    }
    __syncthreads();

    // per-node (m, deg, self, class-rank) for 3 strided entries per thread
    int mj[3], degk[3], selfk[3], cls[3], rank[3];
    int psum = 0;
#pragma unroll
    for (int k = 0; k < 3; ++k) {
        int idx = t + k * HT;
        int m = 0, dg = 0, sf = 0;
        if (idx < nlocal) {
            int c = lh[idx];
            int slocal = lo + idx;
            sf = (slocal < NCOARSE) ? (b * NCOARSE + slocal + 1) : 0;  // coarse row + 1
            m = (c >> 16) + (sf ? 1 : 0);
            dg = (c & 0xFFFF) + 1;
            cls[k] = min(m, NCLS - 1);
            rank[k] = atomicAdd(&ccnt[cls[k]], 1);
        }
        mj[k] = m; degk[k] = dg; selfk[k] = sf;
        psum += m;
    }
    sm[t] = psum; __syncthreads();
    for (int off = 1; off < HT; off <<= 1) {        // inclusive block scan
        int add = (t >= off) ? sm[t - off] : 0;
        __syncthreads();
        sm[t] += add;
        __syncthreads();
    }
    if (t == HT - 1) gbase = atomicAdd(gctr, sm[HT - 1]);
    if (t == 0) {                                   // exclusive scan of class counts
        int run = 0;
#pragma unroll
        for (int c = 0; c < NCLS; ++c) { int v = ccnt[c]; ccnt[c] = run; run += v; }
    }
    __syncthreads();

    int run = gbase + sm[t] - psum;                 // exclusive base for this thread
#pragma unroll
    for (int k = 0; k < 3; ++k) {
        int idx = t + k * HT;
        if (idx < nlocal) {
            int gf = rebase + idx;
            float rq = rsqrtf((float)degk[k]);
            meta[gf] = make_int2(run, mj[k]);
            rsd[idx] = rq;
            ord[rebase + ccnt[cls[k]] + rank[k]] = gf;
            int cur2 = run;
            if (selfk[k]) {
                int rv = selfk[k] - 1;
                normc[rv] = rq;                     // rsqrt(deg) of this coarse node
                vals2[cur2] = make_int2(rv, __float_as_int(rq));
                ++cur2;
            }
            lh[idx] = cur2;                         // becomes cursor
            run += mj[k];
        }
    }
    __syncthreads();

    // fill pass: segment is L2-hot
    for (int i = t; i < ne; i += HT) {
        unsigned u = seg[i];
        int l = (int)(u >> 18);
        int rc = (int)(u & 0x3FFFFu);
        if (rc && l < nlocal) {
            int pos = atomicAdd(&lh[l], 1);
            vals2[pos] = make_int2(rc - 1, __float_as_int(rsd[l]));
        }
    }
}

// finalize coefficients: entry.y = rsqrt(deg_dst) * normc[entry.x]
__global__ __launch_bounds__(256) void k_coef(int2* __restrict__ vals2, const float* __restrict__ normc,
                                              const int* __restrict__ gctr) {
    int j = blockIdx.x * 256 + threadIdx.x;
    if (j >= *gctr) return;
    int2 e = vals2[j];
    vals2[j] = make_int2(e.x, __float_as_int(__int_as_float(e.y) * normc[e.x]));
}

// h[M,64](bf16) = x[M,128] @ W[128,64]
__global__ __launch_bounds__(256) void k_gemm(const float* __restrict__ x, const float* __restrict__ W,
                                              __hip_bfloat16* __restrict__ h, int M) {
    __shared__ float sXT[KC][BM];
    __shared__ float sW[KC][COUT];
    int t = threadIdx.x;
    int row0 = blockIdx.x * BM;
    int tr = (t & 31) * 4;
    int tc = (t >> 5) * 8;
    float acc[4][8];
#pragma unroll
    for (int i = 0; i < 4; ++i)
#pragma unroll
        for (int j = 0; j < 8; ++j) acc[i][j] = 0.f;

    for (int k0 = 0; k0 < CIN; k0 += KC) {
        __syncthreads();
#pragma unroll
        for (int it = 0; it < 8; ++it) {
            int i = it * 256 + t;
            int row = i >> 4;
            int kq  = (i & 15) * 4;
            int gr = row0 + row;
            float4 v = (gr < M) ? *reinterpret_cast<const float4*>(&x[(size_t)gr * CIN + k0 + kq])
                                : make_float4(0.f, 0.f, 0.f, 0.f);
            sXT[kq + 0][row] = v.x;
            sXT[kq + 1][row] = v.y;
            sXT[kq + 2][row] = v.z;
            sXT[kq + 3][row] = v.w;
        }
#pragma unroll
        for (int it = 0; it < 4; ++it) {
            int i = it * 256 + t;
            int kk = i >> 4;
            int cq = (i & 15) * 4;
            *reinterpret_cast<float4*>(&sW[kk][cq]) =
                *reinterpret_cast<const float4*>(&W[(size_t)(k0 + kk) * COUT + cq]);
        }
        __syncthreads();
#pragma unroll 8
        for (int k = 0; k < KC; ++k) {
            float4 xa = *reinterpret_cast<const float4*>(&sXT[k][tr]);
            float4 wa = *reinterpret_cast<const float4*>(&sW[k][tc]);
            float4 wb = *reinterpret_cast<const float4*>(&sW[k][tc + 4]);
            float xs[4] = { xa.x, xa.y, xa.z, xa.w };
            float ws[8] = { wa.x, wa.y, wa.z, wa.w, wb.x, wb.y, wb.z, wb.w };
#pragma unroll
            for (int i = 0; i < 4; ++i)
#pragma unroll
                for (int j = 0; j < 8; ++j)
                    acc[i][j] = fmaf(xs[i], ws[j], acc[i][j]);
        }
    }
#pragma unroll
    for (int i = 0; i < 4; ++i) {
        int gr = row0 + tr + i;
        if (gr < M) {
            alignas(16) __hip_bfloat16 tmp[8];
#pragma unroll
            for (int j = 0; j < 8; ++j) tmp[j] = __float2bfloat16(acc[i][j]);
            *reinterpret_cast<float4*>(&h[(size_t)gr * COUT + tc]) = *reinterpret_cast<const float4*>(tmp);
        }
    }
}

// fused gather over class-sorted ord[]: wave = 16 nodes as 4 slots x 4 lane-groups.
// Group g (16 lanes) serves node ord[base+4s+g]; each lane owns 8 B of the h row
// (4 channels, uint2 load) -> one load instruction covers 4 CSR entries.
__global__ __launch_bounds__(256) void k_gather(const __hip_bfloat16* __restrict__ h, const int2* __restrict__ meta,
                                                const int2* __restrict__ vals2, const int* __restrict__ ord,
                                                const float* __restrict__ b, float* __restrict__ out, int N16) {
    int wid  = (blockIdx.x * 256 + threadIdx.x) >> 6;
    int lane = threadIdx.x & 63;
    if (wid >= N16) return;
    int g  = lane >> 4;            // lane group -> which node of the slot
    int il = lane & 15;            // uint2 index within the 128 B row
    int base = wid * 16;
    f32x4 bb = *reinterpret_cast<const f32x4*>(&b[il * 4]);

    int nid[4], bg[4], mm[4], mx[4];
    f32x4 acc[4];
    int mmax = 0;
#pragma unroll
    for (int s = 0; s < 4; ++s) {
        nid[s] = ord[base + 4 * s + g];         // group-broadcast load
        int2 Mi = meta[nid[s]];
        bg[s] = Mi.x;
        mm[s] = Mi.y;
        int m1 = max(mm[s], __shfl_xor(mm[s], 16));
        mx[s] = max(m1, __shfl_xor(m1, 32));    // wave-uniform slot max
        acc[s] = (f32x4)(0.f);
        mmax = max(mmax, mx[s]);
    }
    const char* hb = (const char*)h;
    for (int j = 0; j < mmax; ++j) {
#pragma unroll
        for (int s = 0; s < 4; ++s) {
            if (j < mx[s]) {                    // wave-uniform branch
                bool act = j < mm[s];           // uniform within a group
                int2 e = act ? vals2[bg[s] + j] : make_int2(0, 0);
                uint2 hw = act ? *(const uint2*)(hb + (((size_t)(unsigned)e.x) << 7) + il * 8)
                               : make_uint2(0u, 0u);
                float c = __int_as_float(e.y);
                acc[s].x = fmaf(__uint_as_float(hw.x << 16),         c, acc[s].x);
                acc[s].y = fmaf(__uint_as_float(hw.x & 0xFFFF0000u), c, acc[s].y);
                acc[s].z = fmaf(__uint_as_float(hw.y << 16),         c, acc[s].z);
                acc[s].w = fmaf(__uint_as_float(hw.y & 0xFFFF0000u), c, acc[s].w);
            }
        }
    }
#pragma unroll
    for (int s = 0; s < 4; ++s) {
        f32x4 v;
        v.x = acc[s].x + bb.x;
        v.y = acc[s].y + bb.y;
        v.z = acc[s].z + bb.z;
        v.w = acc[s].w + bb.w;
        v.x = v.x > 0.f ? v.x : (__expf(v.x) - 1.0f);
        v.y = v.y > 0.f ? v.y : (__expf(v.y) - 1.0f);
        v.z = v.z > 0.f ? v.z : (__expf(v.z) - 1.0f);
        v.w = v.w > 0.f ? v.w : (__expf(v.w) - 1.0f);
        f32x4* dstp = (f32x4*)(out + ((size_t)(unsigned)nid[s]) * COUT + il * 4);
        __builtin_nontemporal_store(v, dstp);
    }
}

extern "C" void kernel_launch(void* const* d_in, const int* in_sizes, int n_in,
                              void* d_out, int out_size, void* d_ws, size_t ws_size,
                              hipStream_t stream) {
    const float* x    = (const float*)d_in[0];
    const float* W    = (const float*)d_in[1];
    const float* b    = (const float*)d_in[2];
    const int*   edge = (const int*)d_in[3];
    const int Mx = in_sizes[0] / CIN;     // coarse rows (163968)
    const int E  = in_sizes[3] / 2;       // directed edges (3932160)
    const int N  = out_size / COUT;       // fine nodes (655360)
    const int EPS = E / BSAMP;            // edges per sample (61440)

    const int* src = edge;
    const int* dst = edge + E;

    char* ws = (char*)d_ws;
    int2*  meta   = (int2*)ws;     ws += (size_t)N * 8;
    int*   cur    = (int*)ws;      ws += 4096;          // 256 cursors + gctr
    float* normc  = (float*)ws;    ws += (size_t)Mx * 4;
    int*   ord    = (int*)ws;      ws += (size_t)N * 4;
    __hip_bfloat16* h = (__hip_bfloat16*)ws;
    unsigned* pk  = (unsigned*)ws; // aliases h: pk dead before k_gemm writes h
    {
        size_t hbytes  = (size_t)Mx * COUT * 2;                    // 20,987,904
        size_t pkbytes = (size_t)BSAMP * NRNG * SEGCAP * 4;        // 20,971,520
        ws += (hbytes > pkbytes ? hbytes : pkbytes);               // fix: round-12 used pkbytes only
    }
    int2*  vals2  = (int2*)ws;     // up to E + Mx entries (8B each)

    int* gctr = cur + 256;
    const int maxent = E + Mx;
    const int bps = (EPS / 4 + 255) / 256;   // prep blocks per sample (=60)

    k_zero  <<<1, 512, 0, stream>>>(cur);
    k_prep  <<<BSAMP * bps, 256, 0, stream>>>((const int4*)src, (const int4*)dst, pk, cur, EPS, bps);
    k_build <<<BSAMP * NRNG, HT, 0, stream>>>(pk, cur, meta, normc, vals2, ord, gctr);
    k_coef  <<<(maxent + 255) / 256, 256, 0, stream>>>(vals2, normc, gctr);
    k_gemm  <<<(Mx + BM - 1) / BM, 256, 0, stream>>>(x, W, h, Mx);
    k_gather<<<((N / 16) * 64 + 255) / 256, 256, 0, stream>>>(h, meta, vals2, ord, b, (float*)d_out, N / 16);
}

// Round 14
// 166.416 us; speedup vs baseline: 4.1034x; 4.1034x over previous
//
#include <hip/hip_runtime.h>
#include <hip/hip_bf16.h>
#include <math.h>

#define CIN 128
#define COUT 64
#define BM 128
#define KC 64
#define BSAMP 64      // samples in batch (fixed by problem)
#define NFINE 10242   // fine nodes per sample (fixed by problem)
#define NCOARSE 2562  // coarse nodes per sample (fixed by problem)
#define NRNG 4        // node-ranges per sample
#define RS 2561       // ceil(NFINE / NRNG)
#define HT 1024       // threads for build kernel
#define NCLS 17       // degree classes 0..15 and >=16
#define SEGCAP 20480  // slots per (sample,range) segment; mean 15360, sigma ~107
#define CPAD 16       // cursor padding (ints) -> one 64 B line per cursor

typedef float f32x4 __attribute__((ext_vector_type(4)));

// cursors (padded) + gctr = 256*CPAD + 1 ints
__global__ __launch_bounds__(256) void k_zero(int* __restrict__ cur, int n) {
    int i = blockIdx.x * 256 + threadIdx.x;
    if (i < n) cur[i] = 0;
}

// Bucket-scatter prep with per-block LDS staging: each block stages its 1024
// edges into 4 LDS range-buckets, allocates segment space with ONE padded
// global atomic per bucket, then bulk-copies coalesced.
// pk entry = (dst_range_local << 18) | (coarse_row+1); coarse test analytic.
__global__ __launch_bounds__(256) void k_prep(const int4* __restrict__ src4, const int4* __restrict__ dst4,
                                              unsigned* __restrict__ pk, int* __restrict__ cur,
                                              int EPS, int bps) {
    __shared__ unsigned bbuf[NRNG][1024];
    __shared__ int bcnt[NRNG];
    __shared__ int gb[NRNG];
    int t = threadIdx.x;
    int b  = blockIdx.x / bps;
    int il = (blockIdx.x % bps) * 256 + t;
    int n4 = EPS / 4;
    if (t < NRNG) bcnt[t] = 0;
    __syncthreads();
    if (il < n4) {
        size_t i = (size_t)b * n4 + il;
        int4 s = src4[i], d = dst4[i];
        int base = b * NFINE;
#define COMP(c) { \
        int ls = d.c - base; \
        if ((unsigned)ls < (unsigned)NFINE) { \
            int rri = ls / RS; \
            int sl = s.c - base; \
            unsigned rc = ((unsigned)sl < (unsigned)NCOARSE) ? (unsigned)(b * NCOARSE + sl + 1) : 0u; \
            unsigned pv = ((unsigned)(ls - rri * RS) << 18) | rc; \
            int p = atomicAdd(&bcnt[rri], 1); \
            bbuf[rri][p] = pv; } }
        COMP(x) COMP(y) COMP(z) COMP(w)
#undef COMP
    }
    __syncthreads();
    if (t < NRNG) gb[t] = atomicAdd(&cur[(b * NRNG + t) * CPAD], bcnt[t]);
    __syncthreads();
#pragma unroll
    for (int rr = 0; rr < NRNG; ++rr) {
        int n = bcnt[rr];
        int g0 = gb[rr];
        unsigned* seg = pk + (size_t)(b * NRNG + rr) * SEGCAP;
        for (int i = t; i < n; i += 256) {
            int pos = g0 + i;
            if (pos < SEGCAP) seg[pos] = bbuf[rr][i];
        }
    }
}

// One block per (sample, node-range), reading ONLY its own segment.
// Pass 1: LDS histogram (deg low16 | coarse-src count high16).
// Then block scan + one global atomic alloc, meta/normc/self-entry writes,
// degree-class bucketing into ord[] (uniform-m gather waves).
// Pass 2: re-read segment (L2-hot, ~80 KB) and assign vals2 slots.
// Entries written as (r, rsqrt(deg_dst)); k_coef folds in normc[r] afterwards.
__global__ __launch_bounds__(HT) void k_build(const unsigned* __restrict__ pk, const int* __restrict__ cur,
                                              int2* __restrict__ meta, float* __restrict__ normc,
                                              int2* __restrict__ vals2, int* __restrict__ ord,
                                              int* __restrict__ gctr) {
    __shared__ int   lh[RS];      // counts, later cursors
    __shared__ float rsd[RS];     // rsqrt(deg) per local node
    __shared__ int   sm[HT];
    __shared__ int   ccnt[NCLS];
    __shared__ int   gbase;
    int t = threadIdx.x;
    int b = blockIdx.x / NRNG, r = blockIdx.x % NRNG;
    int lo = r * RS;
    int nlocal = min(RS, NFINE - lo);
    int rebase = b * NFINE + lo;
    for (int j = t; j < nlocal; j += HT) lh[j] = 0;
    if (t < NCLS) ccnt[t] = 0;
    __syncthreads();

    const unsigned* seg = pk + (size_t)(b * NRNG + r) * SEGCAP;
    int ne = min(cur[(b * NRNG + r) * CPAD], SEGCAP);
    for (int i = t; i < ne; i += HT) {
        unsigned u = seg[i];
        int l = (int)(u >> 18);
        int rc = (int)(u & 0x3FFFFu);
        if (l < nlocal) atomicAdd(&lh[l], 1 + (rc ? 65536 : 0));
    }
    __syncthreads();

    // per-node (m, deg, self, class-rank) for 3 strided entries per thread
    int mj[3], degk[3], selfk[3], cls[3], rank[3];
    int psum = 0;
#pragma unroll
    for (int k = 0; k < 3; ++k) {
        int idx = t + k * HT;
        int m = 0, dg = 0, sf = 0;
        if (idx < nlocal) {
            int c = lh[idx];
            int slocal = lo + idx;
            sf = (slocal < NCOARSE) ? (b * NCOARSE + slocal + 1) : 0;  // coarse row + 1
            m = (c >> 16) + (sf ? 1 : 0);
            dg = (c & 0xFFFF) + 1;
            cls[k] = min(m, NCLS - 1);
            rank[k] = atomicAdd(&ccnt[cls[k]], 1);
        }
        mj[k] = m; degk[k] = dg; selfk[k] = sf;
        psum += m;
    }
    sm[t] = psum; __syncthreads();
    for (int off = 1; off < HT; off <<= 1) {        // inclusive block scan
        int add = (t >= off) ? sm[t - off] : 0;
        __syncthreads();
        sm[t] += add;
        __syncthreads();
    }
    if (t == HT - 1) gbase = atomicAdd(gctr, sm[HT - 1]);
    if (t == 0) {                                   // exclusive scan of class counts
        int run = 0;
#pragma unroll
        for (int c = 0; c < NCLS; ++c) { int v = ccnt[c]; ccnt[c] = run; run += v; }
    }
    __syncthreads();

    int run = gbase + sm[t] - psum;                 // exclusive base for this thread
#pragma unroll
    for (int k = 0; k < 3; ++k) {
        int idx = t + k * HT;
        if (idx < nlocal) {
            int gf = rebase + idx;
            float rq = rsqrtf((float)degk[k]);
            meta[gf] = make_int2(run, mj[k]);
            rsd[idx] = rq;
            ord[rebase + ccnt[cls[k]] + rank[k]] = gf;
            int cur2 = run;
            if (selfk[k]) {
                int rv = selfk[k] - 1;
                normc[rv] = rq;                     // rsqrt(deg) of this coarse node
                vals2[cur2] = make_int2(rv, __float_as_int(rq));
                ++cur2;
            }
            lh[idx] = cur2;                         // becomes cursor
            run += mj[k];
        }
    }
    __syncthreads();

    // fill pass: segment is L2-hot
    for (int i = t; i < ne; i += HT) {
        unsigned u = seg[i];
        int l = (int)(u >> 18);
        int rc = (int)(u & 0x3FFFFu);
        if (rc && l < nlocal) {
            int pos = atomicAdd(&lh[l], 1);
            vals2[pos] = make_int2(rc - 1, __float_as_int(rsd[l]));
        }
    }
}

// finalize coefficients: entry.y = rsqrt(deg_dst) * normc[entry.x]
__global__ __launch_bounds__(256) void k_coef(int2* __restrict__ vals2, const float* __restrict__ normc,
                                              const int* __restrict__ gctr) {
    int j = blockIdx.x * 256 + threadIdx.x;
    if (j >= *gctr) return;
    int2 e = vals2[j];
    vals2[j] = make_int2(e.x, __float_as_int(__int_as_float(e.y) * normc[e.x]));
}

// h[M,64](bf16) = x[M,128] @ W[128,64]
__global__ __launch_bounds__(256) void k_gemm(const float* __restrict__ x, const float* __restrict__ W,
                                              __hip_bfloat16* __restrict__ h, int M) {
    __shared__ float sXT[KC][BM];
    __shared__ float sW[KC][COUT];
    int t = threadIdx.x;
    int row0 = blockIdx.x * BM;
    int tr = (t & 31) * 4;
    int tc = (t >> 5) * 8;
    float acc[4][8];
#pragma unroll
    for (int i = 0; i < 4; ++i)
#pragma unroll
        for (int j = 0; j < 8; ++j) acc[i][j] = 0.f;

    for (int k0 = 0; k0 < CIN; k0 += KC) {
        __syncthreads();
#pragma unroll
        for (int it = 0; it < 8; ++it) {
            int i = it * 256 + t;
            int row = i >> 4;
            int kq  = (i & 15) * 4;
            int gr = row0 + row;
            float4 v = (gr < M) ? *reinterpret_cast<const float4*>(&x[(size_t)gr * CIN + k0 + kq])
                                : make_float4(0.f, 0.f, 0.f, 0.f);
            sXT[kq + 0][row] = v.x;
            sXT[kq + 1][row] = v.y;
            sXT[kq + 2][row] = v.z;
            sXT[kq + 3][row] = v.w;
        }
#pragma unroll
        for (int it = 0; it < 4; ++it) {
            int i = it * 256 + t;
            int kk = i >> 4;
            int cq = (i & 15) * 4;
            *reinterpret_cast<float4*>(&sW[kk][cq]) =
                *reinterpret_cast<const float4*>(&W[(size_t)(k0 + kk) * COUT + cq]);
        }
        __syncthreads();
#pragma unroll 8
        for (int k = 0; k < KC; ++k) {
            float4 xa = *reinterpret_cast<const float4*>(&sXT[k][tr]);
            float4 wa = *reinterpret_cast<const float4*>(&sW[k][tc]);
            float4 wb = *reinterpret_cast<const float4*>(&sW[k][tc + 4]);
            float xs[4] = { xa.x, xa.y, xa.z, xa.w };
            float ws[8] = { wa.x, wa.y, wa.z, wa.w, wb.x, wb.y, wb.z, wb.w };
#pragma unroll
            for (int i = 0; i < 4; ++i)
#pragma unroll
                for (int j = 0; j < 8; ++j)
                    acc[i][j] = fmaf(xs[i], ws[j], acc[i][j]);
        }
    }
#pragma unroll
    for (int i = 0; i < 4; ++i) {
        int gr = row0 + tr + i;
        if (gr < M) {
            alignas(16) __hip_bfloat16 tmp[8];
#pragma unroll
            for (int j = 0; j < 8; ++j) tmp[j] = __float2bfloat16(acc[i][j]);
            *reinterpret_cast<float4*>(&h[(size_t)gr * COUT + tc]) = *reinterpret_cast<const float4*>(tmp);
        }
    }
}

// fused gather over class-sorted ord[]: wave = 16 nodes as 4 slots x 4 lane-groups.
// Group g (16 lanes) serves node ord[base+4s+g]; each lane owns 8 B of the h row
// (4 channels, uint2 load) -> one load instruction covers 4 CSR entries.
__global__ __launch_bounds__(256) void k_gather(const __hip_bfloat16* __restrict__ h, const int2* __restrict__ meta,
                                                const int2* __restrict__ vals2, const int* __restrict__ ord,
                                                const float* __restrict__ b, float* __restrict__ out, int N16) {
    int wid  = (blockIdx.x * 256 + threadIdx.x) >> 6;
    int lane = threadIdx.x & 63;
    if (wid >= N16) return;
    int g  = lane >> 4;            // lane group -> which node of the slot
    int il = lane & 15;            // uint2 index within the 128 B row
    int base = wid * 16;
    f32x4 bb = *reinterpret_cast<const f32x4*>(&b[il * 4]);

    int nid[4], bg[4], mm[4], mx[4];
    f32x4 acc[4];
    int mmax = 0;
#pragma unroll
    for (int s = 0; s < 4; ++s) {
        nid[s] = ord[base + 4 * s + g];         // group-broadcast load
        int2 Mi = meta[nid[s]];
        bg[s] = Mi.x;
        mm[s] = Mi.y;
        int m1 = max(mm[s], __shfl_xor(mm[s], 16));
        mx[s] = max(m1, __shfl_xor(m1, 32));    // wave-uniform slot max
        acc[s] = (f32x4)(0.f);
        mmax = max(mmax, mx[s]);
    }
    const char* hb = (const char*)h;
    for (int j = 0; j < mmax; ++j) {
#pragma unroll
        for (int s = 0; s < 4; ++s) {
            if (j < mx[s]) {                    // wave-uniform branch
                bool act = j < mm[s];           // uniform within a group
                int2 e = act ? vals2[bg[s] + j] : make_int2(0, 0);
                uint2 hw = act ? *(const uint2*)(hb + (((size_t)(unsigned)e.x) << 7) + il * 8)
                               : make_uint2(0u, 0u);
                float c = __int_as_float(e.y);
                acc[s].x = fmaf(__uint_as_float(hw.x << 16),         c, acc[s].x);
                acc[s].y = fmaf(__uint_as_float(hw.x & 0xFFFF0000u), c, acc[s].y);
                acc[s].z = fmaf(__uint_as_float(hw.y << 16),         c, acc[s].z);
                acc[s].w = fmaf(__uint_as_float(hw.y & 0xFFFF0000u), c, acc[s].w);
            }
        }
    }
#pragma unroll
    for (int s = 0; s < 4; ++s) {
        f32x4 v;
        v.x = acc[s].x + bb.x;
        v.y = acc[s].y + bb.y;
        v.z = acc[s].z + bb.z;
        v.w = acc[s].w + bb.w;
        v.x = v.x > 0.f ? v.x : (__expf(v.x) - 1.0f);
        v.y = v.y > 0.f ? v.y : (__expf(v.y) - 1.0f);
        v.z = v.z > 0.f ? v.z : (__expf(v.z) - 1.0f);
        v.w = v.w > 0.f ? v.w : (__expf(v.w) - 1.0f);
        f32x4* dstp = (f32x4*)(out + ((size_t)(unsigned)nid[s]) * COUT + il * 4);
        __builtin_nontemporal_store(v, dstp);
    }
}

extern "C" void kernel_launch(void* const* d_in, const int* in_sizes, int n_in,
                              void* d_out, int out_size, void* d_ws, size_t ws_size,
                              hipStream_t stream) {
    const float* x    = (const float*)d_in[0];
    const float* W    = (const float*)d_in[1];
    const float* b    = (const float*)d_in[2];
    const int*   edge = (const int*)d_in[3];
    const int Mx = in_sizes[0] / CIN;     // coarse rows (163968)
    const int E  = in_sizes[3] / 2;       // directed edges (3932160)
    const int N  = out_size / COUT;       // fine nodes (655360)
    const int EPS = E / BSAMP;            // edges per sample (61440)

    const int* src = edge;
    const int* dst = edge + E;

    char* ws = (char*)d_ws;
    int2*  meta   = (int2*)ws;     ws += (size_t)N * 8;
    int*   cur    = (int*)ws;      ws += (256 * CPAD + 256) * 4;   // padded cursors + gctr
    float* normc  = (float*)ws;    ws += (size_t)Mx * 4;
    int*   ord    = (int*)ws;      ws += (size_t)N * 4;
    __hip_bfloat16* h = (__hip_bfloat16*)ws;
    unsigned* pk  = (unsigned*)ws; // aliases h: pk dead before k_gemm writes h
    {
        size_t hbytes  = (size_t)Mx * COUT * 2;                    // 20,987,904
        size_t pkbytes = (size_t)BSAMP * NRNG * SEGCAP * 4;        // 20,971,520
        ws += (hbytes > pkbytes ? hbytes : pkbytes);
    }
    int2*  vals2  = (int2*)ws;     // up to E + Mx entries (8B each)

    int* gctr = cur + 256 * CPAD;
    const int maxent = E + Mx;
    const int bps = (EPS / 4 + 255) / 256;   // prep blocks per sample (=60)
    const int nzero = 256 * CPAD + 1;

    k_zero  <<<(nzero + 255) / 256, 256, 0, stream>>>(cur, nzero);
    k_prep  <<<BSAMP * bps, 256, 0, stream>>>((const int4*)src, (const int4*)dst, pk, cur, EPS, bps);
    k_build <<<BSAMP * NRNG, HT, 0, stream>>>(pk, cur, meta, normc, vals2, ord, gctr);
    k_coef  <<<(maxent + 255) / 256, 256, 0, stream>>>(vals2, normc, gctr);
    k_gemm  <<<(Mx + BM - 1) / BM, 256, 0, stream>>>(x, W, h, Mx);
    k_gather<<<((N / 16) * 64 + 255) / 256, 256, 0, stream>>>(h, meta, vals2, ord, b, (float*)d_out, N / 16);
}

// Round 15
// 154.103 us; speedup vs baseline: 4.4312x; 1.0799x over previous
//
#include <hip/hip_runtime.h>
#include <hip/hip_bf16.h>
#include <math.h>

#define CIN 128
#define COUT 64
#define BM 128
#define KC 64
#define BSAMP 64      // samples in batch (fixed by problem)
#define NFINE 10242   // fine nodes per sample (fixed by problem)
#define NCOARSE 2562  // coarse nodes per sample (fixed by problem)
#define NRNG 4        // node-ranges per sample
#define RS 2561       // ceil(NFINE / NRNG)
#define HT 1024       // threads for build kernel
#define NCLS 17       // degree classes 0..15 and >=16
#define SEGCAP 20480  // slots per (sample,range) segment; mean 15360, sigma ~107
#define CPAD 16       // cursor padding (ints) -> one 64 B line per cursor

typedef float f32x4 __attribute__((ext_vector_type(4)));

// cursors (padded) + gctr
__global__ __launch_bounds__(256) void k_zero(int* __restrict__ cur, int n) {
    int i = blockIdx.x * 256 + threadIdx.x;
    if (i < n) cur[i] = 0;
}

// Bucket-scatter prep with per-block LDS staging: each block stages its 1024
// edges into 4 LDS range-buckets, allocates segment space with ONE padded
// global atomic per bucket, then bulk-copies coalesced.
// pk entry = (dst_range_local << 18) | (coarse_row+1); coarse test analytic.
__global__ __launch_bounds__(256) void k_prep(const int4* __restrict__ src4, const int4* __restrict__ dst4,
                                              unsigned* __restrict__ pk, int* __restrict__ cur,
                                              int EPS, int bps) {
    __shared__ unsigned bbuf[NRNG][1024];
    __shared__ int bcnt[NRNG];
    __shared__ int gb[NRNG];
    int t = threadIdx.x;
    int b  = blockIdx.x / bps;
    int il = (blockIdx.x % bps) * 256 + t;
    int n4 = EPS / 4;
    if (t < NRNG) bcnt[t] = 0;
    __syncthreads();
    if (il < n4) {
        size_t i = (size_t)b * n4 + il;
        int4 s = src4[i], d = dst4[i];
        int base = b * NFINE;
#define COMP(c) { \
        int ls = d.c - base; \
        if ((unsigned)ls < (unsigned)NFINE) { \
            int rri = ls / RS; \
            int sl = s.c - base; \
            unsigned rc = ((unsigned)sl < (unsigned)NCOARSE) ? (unsigned)(b * NCOARSE + sl + 1) : 0u; \
            unsigned pv = ((unsigned)(ls - rri * RS) << 18) | rc; \
            int p = atomicAdd(&bcnt[rri], 1); \
            bbuf[rri][p] = pv; } }
        COMP(x) COMP(y) COMP(z) COMP(w)
#undef COMP
    }
    __syncthreads();
    if (t < NRNG) gb[t] = atomicAdd(&cur[(b * NRNG + t) * CPAD], bcnt[t]);
    __syncthreads();
#pragma unroll
    for (int rr = 0; rr < NRNG; ++rr) {
        int n = bcnt[rr];
        int g0 = gb[rr];
        unsigned* seg = pk + (size_t)(b * NRNG + rr) * SEGCAP;
        for (int i = t; i < n; i += 256) {
            int pos = g0 + i;
            if (pos < SEGCAP) seg[pos] = bbuf[rr][i];
        }
    }
}

// One block per (sample, node-range), reading ONLY its own segment.
// Pass 1: LDS histogram (deg low16 | coarse-src count high16).
// Then block scan + one global atomic alloc, meta/normc/self-entry writes,
// degree-class bucketing into ord[] (uniform-m gather waves).
// Pass 2: re-read segment (L2-hot) and assign vals slots (just coarse row r:
// the coefficient is folded into h (normc side) and meta.deg (dst side)).
__global__ __launch_bounds__(HT) void k_build(const unsigned* __restrict__ pk, const int* __restrict__ cur,
                                              int2* __restrict__ meta, float* __restrict__ normc,
                                              int* __restrict__ vals, int* __restrict__ ord,
                                              int* __restrict__ gctr) {
    __shared__ int   lh[RS];      // counts, later cursors
    __shared__ int   sm[HT];
    __shared__ int   ccnt[NCLS];
    __shared__ int   gbase;
    int t = threadIdx.x;
    int b = blockIdx.x / NRNG, r = blockIdx.x % NRNG;
    int lo = r * RS;
    int nlocal = min(RS, NFINE - lo);
    int rebase = b * NFINE + lo;
    for (int j = t; j < nlocal; j += HT) lh[j] = 0;
    if (t < NCLS) ccnt[t] = 0;
    __syncthreads();

    const unsigned* seg = pk + (size_t)(b * NRNG + r) * SEGCAP;
    int ne = min(cur[(b * NRNG + r) * CPAD], SEGCAP);
    for (int i = t; i < ne; i += HT) {
        unsigned u = seg[i];
        int l = (int)(u >> 18);
        int rc = (int)(u & 0x3FFFFu);
        if (l < nlocal) atomicAdd(&lh[l], 1 + (rc ? 65536 : 0));
    }
    __syncthreads();

    // per-node (m, deg, self, class-rank) for 3 strided entries per thread
    int mj[3], degk[3], selfk[3], cls[3], rank[3];
    int psum = 0;
#pragma unroll
    for (int k = 0; k < 3; ++k) {
        int idx = t + k * HT;
        int m = 0, dg = 0, sf = 0;
        if (idx < nlocal) {
            int c = lh[idx];
            int slocal = lo + idx;
            sf = (slocal < NCOARSE) ? (b * NCOARSE + slocal + 1) : 0;  // coarse row + 1
            m = (c >> 16) + (sf ? 1 : 0);
            dg = (c & 0xFFFF) + 1;
            cls[k] = min(m, NCLS - 1);
            rank[k] = atomicAdd(&ccnt[cls[k]], 1);
        }
        mj[k] = m; degk[k] = dg; selfk[k] = sf;
        psum += m;
    }
    sm[t] = psum; __syncthreads();
    for (int off = 1; off < HT; off <<= 1) {        // inclusive block scan
        int add = (t >= off) ? sm[t - off] : 0;
        __syncthreads();
        sm[t] += add;
        __syncthreads();
    }
    if (t == HT - 1) gbase = atomicAdd(gctr, sm[HT - 1]);
    if (t == 0) {                                   // exclusive scan of class counts
        int run = 0;
#pragma unroll
        for (int c = 0; c < NCLS; ++c) { int v = ccnt[c]; ccnt[c] = run; run += v; }
    }
    __syncthreads();

    int run = gbase + sm[t] - psum;                 // exclusive base for this thread
#pragma unroll
    for (int k = 0; k < 3; ++k) {
        int idx = t + k * HT;
        if (idx < nlocal) {
            int gf = rebase + idx;
            meta[gf] = make_int2(run, mj[k] | (degk[k] << 16));
            ord[rebase + ccnt[cls[k]] + rank[k]] = gf;
            int cur2 = run;
            if (selfk[k]) {
                int rv = selfk[k] - 1;
                normc[rv] = rsqrtf((float)degk[k]);  // rsqrt(deg) of this coarse node
                vals[cur2] = rv;                     // self entry: h'[rv]*rsqrt(deg)=h/deg
                ++cur2;
            }
            lh[idx] = cur2;                         // becomes cursor
            run += mj[k];
        }
    }
    __syncthreads();

    // fill pass: segment is L2-hot
    for (int i = t; i < ne; i += HT) {
        unsigned u = seg[i];
        int l = (int)(u >> 18);
        int rc = (int)(u & 0x3FFFFu);
        if (rc && l < nlocal) {
            int pos = atomicAdd(&lh[l], 1);
            vals[pos] = rc - 1;
        }
    }
}

// h[M,64](bf16) = (x[M,128] @ W[128,64]) * normc[row]   (normc folded in)
__global__ __launch_bounds__(256) void k_gemm(const float* __restrict__ x, const float* __restrict__ W,
                                              const float* __restrict__ normc,
                                              __hip_bfloat16* __restrict__ h, int M) {
    __shared__ float sXT[KC][BM];
    __shared__ float sW[KC][COUT];
    int t = threadIdx.x;
    int row0 = blockIdx.x * BM;
    int tr = (t & 31) * 4;
    int tc = (t >> 5) * 8;
    float acc[4][8];
#pragma unroll
    for (int i = 0; i < 4; ++i)
#pragma unroll
        for (int j = 0; j < 8; ++j) acc[i][j] = 0.f;

    for (int k0 = 0; k0 < CIN; k0 += KC) {
        __syncthreads();
#pragma unroll
        for (int it = 0; it < 8; ++it) {
            int i = it * 256 + t;
            int row = i >> 4;
            int kq  = (i & 15) * 4;
            int gr = row0 + row;
            float4 v = (gr < M) ? *reinterpret_cast<const float4*>(&x[(size_t)gr * CIN + k0 + kq])
                                : make_float4(0.f, 0.f, 0.f, 0.f);
            sXT[kq + 0][row] = v.x;
            sXT[kq + 1][row] = v.y;
            sXT[kq + 2][row] = v.z;
            sXT[kq + 3][row] = v.w;
        }
#pragma unroll
        for (int it = 0; it < 4; ++it) {
            int i = it * 256 + t;
            int kk = i >> 4;
            int cq = (i & 15) * 4;
            *reinterpret_cast<float4*>(&sW[kk][cq]) =
                *reinterpret_cast<const float4*>(&W[(size_t)(k0 + kk) * COUT + cq]);
        }
        __syncthreads();
#pragma unroll 8
        for (int k = 0; k < KC; ++k) {
            float4 xa = *reinterpret_cast<const float4*>(&sXT[k][tr]);
            float4 wa = *reinterpret_cast<const float4*>(&sW[k][tc]);
            float4 wb = *reinterpret_cast<const float4*>(&sW[k][tc + 4]);
            float xs[4] = { xa.x, xa.y, xa.z, xa.w };
            float ws[8] = { wa.x, wa.y, wa.z, wa.w, wb.x, wb.y, wb.z, wb.w };
#pragma unroll
            for (int i = 0; i < 4; ++i)
#pragma unroll
                for (int j = 0; j < 8; ++j)
                    acc[i][j] = fmaf(xs[i], ws[j], acc[i][j]);
        }
    }
#pragma unroll
    for (int i = 0; i < 4; ++i) {
        int gr = row0 + tr + i;
        if (gr < M) {
            float sc = normc[gr];
            alignas(16) __hip_bfloat16 tmp[8];
#pragma unroll
            for (int j = 0; j < 8; ++j) tmp[j] = __float2bfloat16(acc[i][j] * sc);
            *reinterpret_cast<float4*>(&h[(size_t)gr * COUT + tc]) = *reinterpret_cast<const float4*>(tmp);
        }
    }
}

// fused gather over class-sorted ord[]: wave = 16 nodes as 4 slots x 4 lane-groups.
// Group g (16 lanes) serves node ord[base+4s+g]; each lane owns 8 B of the h row.
// Inner loop is pure h'-row accumulation; rsqrt(deg_dst) applied once at the end.
__global__ __launch_bounds__(256) void k_gather(const __hip_bfloat16* __restrict__ h, const int2* __restrict__ meta,
                                                const int* __restrict__ vals, const int* __restrict__ ord,
                                                const float* __restrict__ b, float* __restrict__ out, int N16) {
    int wid  = (blockIdx.x * 256 + threadIdx.x) >> 6;
    int lane = threadIdx.x & 63;
    if (wid >= N16) return;
    int g  = lane >> 4;            // lane group -> which node of the slot
    int il = lane & 15;            // uint2 index within the 128 B row
    int base = wid * 16;
    f32x4 bb = *reinterpret_cast<const f32x4*>(&b[il * 4]);

    int nid[4], bg[4], mm[4], mx[4];
    float nf[4];
    f32x4 acc[4];
    int mmax = 0;
#pragma unroll
    for (int s = 0; s < 4; ++s) {
        nid[s] = ord[base + 4 * s + g];         // group-broadcast load
        int2 Mi = meta[nid[s]];
        bg[s] = Mi.x;
        mm[s] = Mi.y & 0xFFFF;
        nf[s] = rsqrtf((float)(Mi.y >> 16));    // rsqrt(deg_dst)
        int m1 = max(mm[s], __shfl_xor(mm[s], 16));
        mx[s] = max(m1, __shfl_xor(m1, 32));    // wave-uniform slot max
        acc[s] = (f32x4)(0.f);
        mmax = max(mmax, mx[s]);
    }
    const char* hb = (const char*)h;
    for (int j = 0; j < mmax; ++j) {
#pragma unroll
        for (int s = 0; s < 4; ++s) {
            if (j < mx[s]) {                    // wave-uniform branch
                bool act = j < mm[s];           // uniform within a group
                int e = act ? vals[bg[s] + j] : 0;
                uint2 hw = act ? *(const uint2*)(hb + (((size_t)(unsigned)e) << 7) + il * 8)
                               : make_uint2(0u, 0u);
                acc[s].x += __uint_as_float(hw.x << 16);
                acc[s].y += __uint_as_float(hw.x & 0xFFFF0000u);
                acc[s].z += __uint_as_float(hw.y << 16);
                acc[s].w += __uint_as_float(hw.y & 0xFFFF0000u);
            }
        }
    }
#pragma unroll
    for (int s = 0; s < 4; ++s) {
        f32x4 v;
        v.x = fmaf(acc[s].x, nf[s], bb.x);
        v.y = fmaf(acc[s].y, nf[s], bb.y);
        v.z = fmaf(acc[s].z, nf[s], bb.z);
        v.w = fmaf(acc[s].w, nf[s], bb.w);
        v.x = v.x > 0.f ? v.x : (__expf(v.x) - 1.0f);
        v.y = v.y > 0.f ? v.y : (__expf(v.y) - 1.0f);
        v.z = v.z > 0.f ? v.z : (__expf(v.z) - 1.0f);
        v.w = v.w > 0.f ? v.w : (__expf(v.w) - 1.0f);
        f32x4* dstp = (f32x4*)(out + ((size_t)(unsigned)nid[s]) * COUT + il * 4);
        __builtin_nontemporal_store(v, dstp);
    }
}

extern "C" void kernel_launch(void* const* d_in, const int* in_sizes, int n_in,
                              void* d_out, int out_size, void* d_ws, size_t ws_size,
                              hipStream_t stream) {
    const float* x    = (const float*)d_in[0];
    const float* W    = (const float*)d_in[1];
    const float* b    = (const float*)d_in[2];
    const int*   edge = (const int*)d_in[3];
    const int Mx = in_sizes[0] / CIN;     // coarse rows (163968)
    const int E  = in_sizes[3] / 2;       // directed edges (3932160)
    const int N  = out_size / COUT;       // fine nodes (655360)
    const int EPS = E / BSAMP;            // edges per sample (61440)

    const int* src = edge;
    const int* dst = edge + E;

    char* ws = (char*)d_ws;
    int2*  meta   = (int2*)ws;     ws += (size_t)N * 8;
    int*   cur    = (int*)ws;      ws += (256 * CPAD + 256) * 4;   // padded cursors + gctr
    float* normc  = (float*)ws;    ws += (size_t)Mx * 4;
    int*   ord    = (int*)ws;      ws += (size_t)N * 4;
    __hip_bfloat16* h = (__hip_bfloat16*)ws;
    unsigned* pk  = (unsigned*)ws; // aliases h: pk dead before k_gemm writes h
    {
        size_t hbytes  = (size_t)Mx * COUT * 2;                    // 20,987,904
        size_t pkbytes = (size_t)BSAMP * NRNG * SEGCAP * 4;        // 20,971,520
        ws += (hbytes > pkbytes ? hbytes : pkbytes);
    }
    int*   vals   = (int*)ws;      // up to E + Mx entries (4B each)

    int* gctr = cur + 256 * CPAD;
    const int bps = (EPS / 4 + 255) / 256;   // prep blocks per sample (=60)
    const int nzero = 256 * CPAD + 1;

    k_zero  <<<(nzero + 255) / 256, 256, 0, stream>>>(cur, nzero);
    k_prep  <<<BSAMP * bps, 256, 0, stream>>>((const int4*)src, (const int4*)dst, pk, cur, EPS, bps);
    k_build <<<BSAMP * NRNG, HT, 0, stream>>>(pk, cur, meta, normc, vals, ord, gctr);
    k_gemm  <<<(Mx + BM - 1) / BM, 256, 0, stream>>>(x, W, normc, h, Mx);
    k_gather<<<((N / 16) * 64 + 255) / 256, 256, 0, stream>>>(h, meta, vals, ord, b, (float*)d_out, N / 16);
}

// Round 16
// 149.842 us; speedup vs baseline: 4.5573x; 1.0284x over previous
//
#include <hip/hip_runtime.h>
#include <hip/hip_bf16.h>
#include <math.h>

#define CIN 128
#define COUT 64
#define BSAMP 64      // samples in batch (fixed by problem)
#define NFINE 10242   // fine nodes per sample (fixed by problem)
#define NCOARSE 2562  // coarse nodes per sample (fixed by problem)
#define NRNG 4        // node-ranges per sample
#define RS 2561       // ceil(NFINE / NRNG)
#define HT 1024       // threads for build kernel
#define NCLS 17       // degree classes 0..15 and >=16
#define SEGCAP 20480  // slots per (sample,range) segment; mean 15360, sigma ~107
#define CPAD 16       // cursor padding (ints) -> one 64 B line per cursor

typedef float f32x4 __attribute__((ext_vector_type(4)));
typedef short s16x8 __attribute__((ext_vector_type(8)));

// cursors (padded) + gctr
__global__ __launch_bounds__(256) void k_zero(int* __restrict__ cur, int n) {
    int i = blockIdx.x * 256 + threadIdx.x;
    if (i < n) cur[i] = 0;
}

// Bucket-scatter prep with per-block LDS staging (unchanged from round 15).
__global__ __launch_bounds__(256) void k_prep(const int4* __restrict__ src4, const int4* __restrict__ dst4,
                                              unsigned* __restrict__ pk, int* __restrict__ cur,
                                              int EPS, int bps) {
    __shared__ unsigned bbuf[NRNG][1024];
    __shared__ int bcnt[NRNG];
    __shared__ int gb[NRNG];
    int t = threadIdx.x;
    int b  = blockIdx.x / bps;
    int il = (blockIdx.x % bps) * 256 + t;
    int n4 = EPS / 4;
    if (t < NRNG) bcnt[t] = 0;
    __syncthreads();
    if (il < n4) {
        size_t i = (size_t)b * n4 + il;
        int4 s = src4[i], d = dst4[i];
        int base = b * NFINE;
#define COMP(c) { \
        int ls = d.c - base; \
        if ((unsigned)ls < (unsigned)NFINE) { \
            int rri = ls / RS; \
            int sl = s.c - base; \
            unsigned rc = ((unsigned)sl < (unsigned)NCOARSE) ? (unsigned)(b * NCOARSE + sl + 1) : 0u; \
            unsigned pv = ((unsigned)(ls - rri * RS) << 18) | rc; \
            int p = atomicAdd(&bcnt[rri], 1); \
            bbuf[rri][p] = pv; } }
        COMP(x) COMP(y) COMP(z) COMP(w)
#undef COMP
    }
    __syncthreads();
    if (t < NRNG) gb[t] = atomicAdd(&cur[(b * NRNG + t) * CPAD], bcnt[t]);
    __syncthreads();
#pragma unroll
    for (int rr = 0; rr < NRNG; ++rr) {
        int n = bcnt[rr];
        int g0 = gb[rr];
        unsigned* seg = pk + (size_t)(b * NRNG + rr) * SEGCAP;
        for (int i = t; i < n; i += 256) {
            int pos = g0 + i;
            if (pos < SEGCAP) seg[pos] = bbuf[rr][i];
        }
    }
}

// CSR build (unchanged from round 15).
__global__ __launch_bounds__(HT) void k_build(const unsigned* __restrict__ pk, const int* __restrict__ cur,
                                              int2* __restrict__ meta, float* __restrict__ normc,
                                              int* __restrict__ vals, int* __restrict__ ord,
                                              int* __restrict__ gctr) {
    __shared__ int   lh[RS];
    __shared__ int   sm[HT];
    __shared__ int   ccnt[NCLS];
    __shared__ int   gbase;
    int t = threadIdx.x;
    int b = blockIdx.x / NRNG, r = blockIdx.x % NRNG;
    int lo = r * RS;
    int nlocal = min(RS, NFINE - lo);
    int rebase = b * NFINE + lo;
    for (int j = t; j < nlocal; j += HT) lh[j] = 0;
    if (t < NCLS) ccnt[t] = 0;
    __syncthreads();

    const unsigned* seg = pk + (size_t)(b * NRNG + r) * SEGCAP;
    int ne = min(cur[(b * NRNG + r) * CPAD], SEGCAP);
    for (int i = t; i < ne; i += HT) {
        unsigned u = seg[i];
        int l = (int)(u >> 18);
        int rc = (int)(u & 0x3FFFFu);
        if (l < nlocal) atomicAdd(&lh[l], 1 + (rc ? 65536 : 0));
    }
    __syncthreads();

    int mj[3], degk[3], selfk[3], cls[3], rank[3];
    int psum = 0;
#pragma unroll
    for (int k = 0; k < 3; ++k) {
        int idx = t + k * HT;
        int m = 0, dg = 0, sf = 0;
        if (idx < nlocal) {
            int c = lh[idx];
            int slocal = lo + idx;
            sf = (slocal < NCOARSE) ? (b * NCOARSE + slocal + 1) : 0;
            m = (c >> 16) + (sf ? 1 : 0);
            dg = (c & 0xFFFF) + 1;
            cls[k] = min(m, NCLS - 1);
            rank[k] = atomicAdd(&ccnt[cls[k]], 1);
        }
        mj[k] = m; degk[k] = dg; selfk[k] = sf;
        psum += m;
    }
    sm[t] = psum; __syncthreads();
    for (int off = 1; off < HT; off <<= 1) {
        int add = (t >= off) ? sm[t - off] : 0;
        __syncthreads();
        sm[t] += add;
        __syncthreads();
    }
    if (t == HT - 1) gbase = atomicAdd(gctr, sm[HT - 1]);
    if (t == 0) {
        int run = 0;
#pragma unroll
        for (int c = 0; c < NCLS; ++c) { int v = ccnt[c]; ccnt[c] = run; run += v; }
    }
    __syncthreads();

    int run = gbase + sm[t] - psum;
#pragma unroll
    for (int k = 0; k < 3; ++k) {
        int idx = t + k * HT;
        if (idx < nlocal) {
            int gf = rebase + idx;
            meta[gf] = make_int2(run, mj[k] | (degk[k] << 16));
            ord[rebase + ccnt[cls[k]] + rank[k]] = gf;
            int cur2 = run;
            if (selfk[k]) {
                int rv = selfk[k] - 1;
                normc[rv] = rsqrtf((float)degk[k]);
                vals[cur2] = rv;
                ++cur2;
            }
            lh[idx] = cur2;
            run += mj[k];
        }
    }
    __syncthreads();

    for (int i = t; i < ne; i += HT) {
        unsigned u = seg[i];
        int l = (int)(u >> 18);
        int rc = (int)(u & 0x3FFFFu);
        if (rc && l < nlocal) {
            int pos = atomicAdd(&lh[l], 1);
            vals[pos] = rc - 1;
        }
    }
}

// MFMA GEMM: h[M,64](bf16) = (x[M,128] @ W[128,64]) * normc[row]
// One 16-row tile per wave, 4 waves/block. A-fragments straight from global x
// (lane: row = l&15, k = (l>>4)*8 + j + ks*32); W^T staged bf16 in LDS (+8 pad);
// B-fragments in registers (col = l&15, same k split). C/D: col=l&15,
// row=(l>>4)*4+reg (verified layout).
__global__ __launch_bounds__(256) void k_gemm(const float* __restrict__ x, const float* __restrict__ W,
                                              const float* __restrict__ normc,
                                              __hip_bfloat16* __restrict__ h, int M) {
    __shared__ unsigned short sWT[COUT][CIN + 8];   // W^T bf16, padded
    int t = threadIdx.x;
    for (int i = t; i < CIN * COUT; i += 256) {
        int k = i >> 6, c = i & 63;
        __hip_bfloat16 v = __float2bfloat16(W[i]);
        sWT[c][k] = *reinterpret_cast<unsigned short*>(&v);
    }
    __syncthreads();

    int wid  = t >> 6;
    int lane = t & 63;
    int r0 = blockIdx.x * 64 + wid * 16;
    if (r0 >= M) return;
    int row = lane & 15;
    int kg  = lane >> 4;

    // B fragments: 4 col-tiles x 4 k-steps
    s16x8 bf[4][4];
#pragma unroll
    for (int ct = 0; ct < 4; ++ct)
#pragma unroll
        for (int ks = 0; ks < 4; ++ks)
            bf[ct][ks] = *reinterpret_cast<const s16x8*>(&sWT[ct * 16 + row][ks * 32 + kg * 8]);

    // A fragments from global x
    const float* xr = x + (size_t)(r0 + row) * CIN + kg * 8;
    s16x8 af[4];
#pragma unroll
    for (int ks = 0; ks < 4; ++ks) {
        float4 a0 = *reinterpret_cast<const float4*>(xr + ks * 32);
        float4 a1 = *reinterpret_cast<const float4*>(xr + ks * 32 + 4);
        alignas(16) __hip_bfloat16 tmp[8];
        tmp[0] = __float2bfloat16(a0.x); tmp[1] = __float2bfloat16(a0.y);
        tmp[2] = __float2bfloat16(a0.z); tmp[3] = __float2bfloat16(a0.w);
        tmp[4] = __float2bfloat16(a1.x); tmp[5] = __float2bfloat16(a1.y);
        tmp[6] = __float2bfloat16(a1.z); tmp[7] = __float2bfloat16(a1.w);
        af[ks] = *reinterpret_cast<const s16x8*>(tmp);
    }

    f32x4 acc[4] = { (f32x4)(0.f), (f32x4)(0.f), (f32x4)(0.f), (f32x4)(0.f) };
#pragma unroll
    for (int ks = 0; ks < 4; ++ks)
#pragma unroll
        for (int ct = 0; ct < 4; ++ct)
            acc[ct] = __builtin_amdgcn_mfma_f32_16x16x32_bf16(af[ks], bf[ct][ks], acc[ct], 0, 0, 0);

    // epilogue: scale by normc[row], store bf16
    float sc[4];
#pragma unroll
    for (int j = 0; j < 4; ++j) sc[j] = normc[r0 + kg * 4 + j];
#pragma unroll
    for (int ct = 0; ct < 4; ++ct) {
#pragma unroll
        for (int j = 0; j < 4; ++j) {
            int rr = r0 + kg * 4 + j;
            h[(size_t)rr * COUT + ct * 16 + row] = __float2bfloat16(acc[ct][j] * sc[j]);
        }
    }
}

// fused gather over class-sorted ord[]: wave = 32 nodes as 8 slots x 4 lane-groups.
// Group g (16 lanes) serves node ord[base+4s+g]; lane owns 8 B of the h row.
__global__ __launch_bounds__(256) void k_gather(const __hip_bfloat16* __restrict__ h, const int2* __restrict__ meta,
                                                const int* __restrict__ vals, const int* __restrict__ ord,
                                                const float* __restrict__ b, float* __restrict__ out, int N32) {
    int wid  = (blockIdx.x * 256 + threadIdx.x) >> 6;
    int lane = threadIdx.x & 63;
    if (wid >= N32) return;
    int g  = lane >> 4;
    int il = lane & 15;
    int base = wid * 32;
    f32x4 bb = *reinterpret_cast<const f32x4*>(&b[il * 4]);

    int nid[8], bg[8], mm[8], mx[8];
    float nf[8];
    f32x4 acc[8];
    int mmax = 0;
#pragma unroll
    for (int s = 0; s < 8; ++s) {
        nid[s] = ord[base + 4 * s + g];
        int2 Mi = meta[nid[s]];
        bg[s] = Mi.x;
        mm[s] = Mi.y & 0xFFFF;
        nf[s] = rsqrtf((float)(Mi.y >> 16));
        int m1 = max(mm[s], __shfl_xor(mm[s], 16));
        mx[s] = max(m1, __shfl_xor(m1, 32));
        acc[s] = (f32x4)(0.f);
        mmax = max(mmax, mx[s]);
    }
    const char* hb = (const char*)h;
    for (int j = 0; j < mmax; ++j) {
#pragma unroll
        for (int s = 0; s < 8; ++s) {
            if (j < mx[s]) {
                bool act = j < mm[s];
                int e = act ? vals[bg[s] + j] : 0;
                uint2 hw = act ? *(const uint2*)(hb + (((size_t)(unsigned)e) << 7) + il * 8)
                               : make_uint2(0u, 0u);
                acc[s].x += __uint_as_float(hw.x << 16);
                acc[s].y += __uint_as_float(hw.x & 0xFFFF0000u);
                acc[s].z += __uint_as_float(hw.y << 16);
                acc[s].w += __uint_as_float(hw.y & 0xFFFF0000u);
            }
        }
    }
#pragma unroll
    for (int s = 0; s < 8; ++s) {
        f32x4 v;
        v.x = fmaf(acc[s].x, nf[s], bb.x);
        v.y = fmaf(acc[s].y, nf[s], bb.y);
        v.z = fmaf(acc[s].z, nf[s], bb.z);
        v.w = fmaf(acc[s].w, nf[s], bb.w);
        v.x = v.x > 0.f ? v.x : (__expf(v.x) - 1.0f);
        v.y = v.y > 0.f ? v.y : (__expf(v.y) - 1.0f);
        v.z = v.z > 0.f ? v.z : (__expf(v.z) - 1.0f);
        v.w = v.w > 0.f ? v.w : (__expf(v.w) - 1.0f);
        f32x4* dstp = (f32x4*)(out + ((size_t)(unsigned)nid[s]) * COUT + il * 4);
        __builtin_nontemporal_store(v, dstp);
    }
}

extern "C" void kernel_launch(void* const* d_in, const int* in_sizes, int n_in,
                              void* d_out, int out_size, void* d_ws, size_t ws_size,
                              hipStream_t stream) {
    const float* x    = (const float*)d_in[0];
    const float* W    = (const float*)d_in[1];
    const float* b    = (const float*)d_in[2];
    const int*   edge = (const int*)d_in[3];
    const int Mx = in_sizes[0] / CIN;     // coarse rows (163968)
    const int E  = in_sizes[3] / 2;       // directed edges (3932160)
    const int N  = out_size / COUT;       // fine nodes (655360)
    const int EPS = E / BSAMP;            // edges per sample (61440)

    const int* src = edge;
    const int* dst = edge + E;

    char* ws = (char*)d_ws;
    int2*  meta   = (int2*)ws;     ws += (size_t)N * 8;
    int*   cur    = (int*)ws;      ws += (256 * CPAD + 256) * 4;   // padded cursors + gctr
    float* normc  = (float*)ws;    ws += (size_t)Mx * 4;
    int*   ord    = (int*)ws;      ws += (size_t)N * 4;
    __hip_bfloat16* h = (__hip_bfloat16*)ws;
    unsigned* pk  = (unsigned*)ws; // aliases h: pk dead before k_gemm writes h
    {
        size_t hbytes  = (size_t)Mx * COUT * 2;                    // 20,987,904
        size_t pkbytes = (size_t)BSAMP * NRNG * SEGCAP * 4;        // 20,971,520
        ws += (hbytes > pkbytes ? hbytes : pkbytes);
    }
    int*   vals   = (int*)ws;      // up to E + Mx entries (4B each)

    int* gctr = cur + 256 * CPAD;
    const int bps = (EPS / 4 + 255) / 256;   // prep blocks per sample (=60)
    const int nzero = 256 * CPAD + 1;

    k_zero  <<<(nzero + 255) / 256, 256, 0, stream>>>(cur, nzero);
    k_prep  <<<BSAMP * bps, 256, 0, stream>>>((const int4*)src, (const int4*)dst, pk, cur, EPS, bps);
    k_build <<<BSAMP * NRNG, HT, 0, stream>>>(pk, cur, meta, normc, vals, ord, gctr);
    k_gemm  <<<(Mx + 63) / 64, 256, 0, stream>>>(x, W, normc, h, Mx);
    k_gather<<<((N / 32) * 64 + 255) / 256, 256, 0, stream>>>(h, meta, vals, ord, b, (float*)d_out, N / 32);
}